// Round 1
// baseline (428.291 us; speedup 1.0000x reference)
//
#include <hip/hip_runtime.h>
#include <hip/hip_bf16.h>

// GptOssMoEExperts on MI355X.
// Key observation: sum(softmax(topk_scores)) == 1.0, so the router is a no-op
// and the output is exactly the shared-expert MLP:
//   out = (gate) * silu(up) @ down_w^T + down_b
// where [gate|up] = hs @ gate_up_w^T + gate_up_b.
//
// Pipeline:
//   K1 convert3: fp32 -> bf16 for hs, gate_up_w, down_w (into ws)
//   K2 gemm1:    hs_bf16 @ gate_up_w^T  (both halves per block), fused
//                bias + gate*silu(up) epilogue -> x_bf16 (4096x2880) in ws
//   K3 gemm2:    x_bf16 @ down_w^T + down_b -> out fp32
// GEMM structure: m97 ladder (128x128 tile, BK=32, 4 waves, global_load_lds
// width 16, mfma_f32_16x16x32_bf16).

typedef __bf16 bf16_t;
typedef bf16_t bf16x8 __attribute__((ext_vector_type(8)));
typedef bf16_t bf16x4 __attribute__((ext_vector_type(4)));
typedef float f32x4 __attribute__((ext_vector_type(4)));

#define SEQ   4096
#define HID   2880
#define INTER 2880

#define BM 128
#define BN 128
#define BK 32

// global -> LDS async copy, 16B per lane. LDS dest must be wave-uniform;
// HW writes base + lane*16.
#define GLD16(srcp, ldsp)                                                     \
  __builtin_amdgcn_global_load_lds(                                           \
      (const __attribute__((address_space(1))) unsigned int*)(srcp),          \
      (__attribute__((address_space(3))) unsigned int*)(ldsp), 16, 0, 0)

// ---------------------------------------------------------------------------
// K1: fp32 -> bf16 conversion of hs, gate_up_w, down_w (contiguous in ws)
// ---------------------------------------------------------------------------
__global__ __launch_bounds__(256) void convert3(const float* __restrict__ a,
                                                const float* __restrict__ b,
                                                const float* __restrict__ c,
                                                bf16_t* __restrict__ o) {
  constexpr size_t na = (size_t)SEQ * HID;          // 11796480
  constexpr size_t nb = (size_t)(2 * INTER) * HID;  // 16588800
  constexpr size_t nc = (size_t)HID * INTER;        // 8294400
  size_t i = ((size_t)blockIdx.x * 256 + threadIdx.x) * 4;
  if (i >= na + nb + nc) return;
  const float* src;
  if (i < na)            src = a + i;
  else if (i < na + nb)  src = b + (i - na);
  else                   src = c + (i - na - nb);
  float4 v = *(const float4*)src;
  bf16x4 r = {(bf16_t)v.x, (bf16_t)v.y, (bf16_t)v.z, (bf16_t)v.w};
  *(bf16x4*)(o + i) = r;
}

// ---------------------------------------------------------------------------
// K2: fused gate_up GEMM + bias + gate*silu(up) -> x (bf16)
// A: (SEQ x HID) bf16, B: gate_up_w (2*INTER x HID) bf16 (row-major, NT GEMM)
// Each block: 128 rows x 128 x-cols; computes BOTH the gate tile (B rows
// col0..col0+127) and the up tile (B rows 2880+col0..) against one A tile.
// ---------------------------------------------------------------------------
__global__ __launch_bounds__(256, 2) void gemm1(const bf16_t* __restrict__ A,
                                                const bf16_t* __restrict__ B,
                                                const float* __restrict__ bias,
                                                bf16_t* __restrict__ X) {
  __shared__ bf16_t sA[BM * BK];
  __shared__ bf16_t sG[BN * BK];
  __shared__ bf16_t sU[BN * BK];

  const int tid = threadIdx.x;
  const int w = tid >> 6;       // wave 0..3
  const int l = tid & 63;       // lane
  const int wr = w >> 1;        // wave row (0..1)
  const int wc = w & 1;         // wave col (0..1)
  const int row0 = blockIdx.x * BM;
  const int col0 = blockIdx.y * BN;

  f32x4 accg[4][4];
  f32x4 accu[4][4];
#pragma unroll
  for (int m = 0; m < 4; ++m)
#pragma unroll
    for (int n = 0; n < 4; ++n) {
      accg[m][n] = (f32x4){0.f, 0.f, 0.f, 0.f};
      accu[m][n] = (f32x4){0.f, 0.f, 0.f, 0.f};
    }

  const int nk = HID / BK;  // 90
  for (int kt = 0; kt < nk; ++kt) {
    const int kbase = kt * BK;
#pragma unroll
    for (int i = 0; i < 2; ++i) {
      const int c = i * 256 + tid;       // chunk 0..511, 16B each
      const int r = c >> 2;              // tile row 0..127
      const int kc = (c & 3) * 8;        // bf16 col within k-slice
      const int ldso = (i * 256 + w * 64) * 8;  // wave-uniform elem offset
      // A tile
      GLD16(A + (size_t)(row0 + r) * HID + kbase + kc, sA + ldso);
      // gate weights (clamp rows >= 2880 for the last, partial N tile)
      const int gr = (col0 + r < INTER) ? (col0 + r) : (INTER - 1);
      GLD16(B + (size_t)gr * HID + kbase + kc, sG + ldso);
      // up weights
      GLD16(B + (size_t)(INTER + gr) * HID + kbase + kc, sU + ldso);
    }
    __syncthreads();  // drains vmcnt: LDS tiles ready

    bf16x8 af[4], gf[4], uf[4];
#pragma unroll
    for (int m = 0; m < 4; ++m)
      af[m] = *(const bf16x8*)&sA[(wr * 64 + m * 16 + (l & 15)) * BK + (l >> 4) * 8];
#pragma unroll
    for (int n = 0; n < 4; ++n) {
      const int br = (wc * 64 + n * 16 + (l & 15)) * BK + (l >> 4) * 8;
      gf[n] = *(const bf16x8*)&sG[br];
      uf[n] = *(const bf16x8*)&sU[br];
    }
#pragma unroll
    for (int m = 0; m < 4; ++m)
#pragma unroll
      for (int n = 0; n < 4; ++n) {
        accg[m][n] = __builtin_amdgcn_mfma_f32_16x16x32_bf16(af[m], gf[n], accg[m][n], 0, 0, 0);
        accu[m][n] = __builtin_amdgcn_mfma_f32_16x16x32_bf16(af[m], uf[n], accu[m][n], 0, 0, 0);
      }
    __syncthreads();  // all waves done reading before next stage overwrites
  }

  // Epilogue: x = (gate + bg) * silu(up + bu), write bf16.
  // C/D layout (m89-verified): col = lane&15, row = (lane>>4)*4 + j.
#pragma unroll
  for (int n = 0; n < 4; ++n) {
    const int col = col0 + wc * 64 + n * 16 + (l & 15);
    if (col < INTER) {
      const float bg = bias[col];
      const float bu = bias[INTER + col];
#pragma unroll
      for (int m = 0; m < 4; ++m) {
        const int rbase = row0 + wr * 64 + m * 16 + (l >> 4) * 4;
#pragma unroll
        for (int j = 0; j < 4; ++j) {
          const float g = accg[m][n][j] + bg;
          const float u = accu[m][n][j] + bu;
          const float su = u / (1.f + __expf(-u));  // silu(u)
          X[(size_t)(rbase + j) * INTER + col] = (bf16_t)(g * su);
        }
      }
    }
  }
}

// ---------------------------------------------------------------------------
// K3: out = x @ down_w^T + down_b  (fp32 out)
// A: x (SEQ x INTER) bf16, B: down_w (HID x INTER) bf16 row-major (NT GEMM)
// ---------------------------------------------------------------------------
__global__ __launch_bounds__(256, 2) void gemm2(const bf16_t* __restrict__ A,
                                                const bf16_t* __restrict__ B,
                                                const float* __restrict__ bias,
                                                float* __restrict__ out) {
  __shared__ bf16_t sA[BM * BK];
  __shared__ bf16_t sB[BN * BK];

  const int tid = threadIdx.x;
  const int w = tid >> 6;
  const int l = tid & 63;
  const int wr = w >> 1;
  const int wc = w & 1;
  const int row0 = blockIdx.x * BM;
  const int col0 = blockIdx.y * BN;

  f32x4 acc[4][4];
#pragma unroll
  for (int m = 0; m < 4; ++m)
#pragma unroll
    for (int n = 0; n < 4; ++n) acc[m][n] = (f32x4){0.f, 0.f, 0.f, 0.f};

  const int nk = INTER / BK;  // 90
  for (int kt = 0; kt < nk; ++kt) {
    const int kbase = kt * BK;
#pragma unroll
    for (int i = 0; i < 2; ++i) {
      const int c = i * 256 + tid;
      const int r = c >> 2;
      const int kc = (c & 3) * 8;
      const int ldso = (i * 256 + w * 64) * 8;
      GLD16(A + (size_t)(row0 + r) * INTER + kbase + kc, sA + ldso);
      const int br = (col0 + r < HID) ? (col0 + r) : (HID - 1);
      GLD16(B + (size_t)br * INTER + kbase + kc, sB + ldso);
    }
    __syncthreads();

    bf16x8 af[4], bf[4];
#pragma unroll
    for (int m = 0; m < 4; ++m)
      af[m] = *(const bf16x8*)&sA[(wr * 64 + m * 16 + (l & 15)) * BK + (l >> 4) * 8];
#pragma unroll
    for (int n = 0; n < 4; ++n)
      bf[n] = *(const bf16x8*)&sB[(wc * 64 + n * 16 + (l & 15)) * BK + (l >> 4) * 8];
#pragma unroll
    for (int m = 0; m < 4; ++m)
#pragma unroll
      for (int n = 0; n < 4; ++n)
        acc[m][n] = __builtin_amdgcn_mfma_f32_16x16x32_bf16(af[m], bf[n], acc[m][n], 0, 0, 0);
    __syncthreads();
  }

#pragma unroll
  for (int n = 0; n < 4; ++n) {
    const int col = col0 + wc * 64 + n * 16 + (l & 15);
    if (col < HID) {
      const float bb = bias[col];
#pragma unroll
      for (int m = 0; m < 4; ++m) {
        const int rbase = row0 + wr * 64 + m * 16 + (l >> 4) * 4;
#pragma unroll
        for (int j = 0; j < 4; ++j)
          out[(size_t)(rbase + j) * HID + col] = acc[m][n][j] + bb;
      }
    }
  }
}

// ---------------------------------------------------------------------------
extern "C" void kernel_launch(void* const* d_in, const int* in_sizes, int n_in,
                              void* d_out, int out_size, void* d_ws, size_t ws_size,
                              hipStream_t stream) {
  (void)in_sizes; (void)n_in; (void)out_size; (void)ws_size;

  const float* hs  = (const float*)d_in[0];  // (4096, 2880)
  // d_in[1] router_w, d_in[2] router_b: unused — sum(softmax(topk)) == 1.
  const float* guw = (const float*)d_in[3];  // (5760, 2880)
  const float* gub = (const float*)d_in[4];  // (5760,)
  const float* dww = (const float*)d_in[5];  // (2880, 2880)
  const float* dwb = (const float*)d_in[6];  // (2880,)
  float* out = (float*)d_out;                // (4096, 2880)

  constexpr size_t n_hs  = (size_t)SEQ * HID;
  constexpr size_t n_guw = (size_t)(2 * INTER) * HID;
  constexpr size_t n_dww = (size_t)HID * INTER;

  bf16_t* ws   = (bf16_t*)d_ws;
  bf16_t* hsb  = ws;
  bf16_t* guwb = hsb + n_hs;
  bf16_t* dwwb = guwb + n_guw;
  bf16_t* xb   = dwwb + n_dww;  // (4096, 2880) bf16

  // K1: convert all fp32 operands to bf16 (36.68M elems, 4/thread)
  const size_t total4 = (n_hs + n_guw + n_dww) / 4;
  const int cgrid = (int)((total4 + 255) / 256);  // 35820
  convert3<<<cgrid, 256, 0, stream>>>(hs, guw, dww, ws);

  // K2: fused gate/up GEMM + silu  (grid: 32 M-tiles x 23 N-tiles)
  dim3 g1(SEQ / BM, (INTER + BN - 1) / BN);
  gemm1<<<g1, 256, 0, stream>>>(hsb, guwb, gub, xb);

  // K3: down GEMM + bias -> fp32 out
  dim3 g2(SEQ / BM, (HID + BN - 1) / BN);
  gemm2<<<g2, 256, 0, stream>>>(xb, dwwb, dwb, out);
}

// Round 2
// 386.958 us; speedup vs baseline: 1.1068x; 1.1068x over previous
//
#include <hip/hip_runtime.h>
#include <hip/hip_bf16.h>

// GptOssMoEExperts on MI355X — round 2: 8-phase-class counted-vmcnt schedule.
// Router is a no-op (sum of softmax == 1): out = (gate * silu(up)) @ down_w^T + down_b.
//
// K1 convert3: fp32 -> bf16 (hs, gate_up_w, down_w)
// K2 gemm1: BM=256 x BN=96 (gate+up fused), BK=32, ring-4 LDS, counted vmcnt(8),
//           XOR-swizzled LDS, setprio MFMA clusters, silu epilogue -> x bf16
// K3 gemm2: BM=256 x BN=192, same schedule -> fp32 out
// Grids: 16x30=480 and 16x15=240 blocks (2880=30*96=15*192; zero partial tiles).

typedef __bf16 bf16_t;
typedef bf16_t bf16x8 __attribute__((ext_vector_type(8)));
typedef bf16_t bf16x4 __attribute__((ext_vector_type(4)));
typedef float f32x4 __attribute__((ext_vector_type(4)));

#define SEQ   4096
#define HID   2880
#define INTER 2880
#define BK    32
#define NT    (HID / BK)  // 90 (both GEMMs have K=2880)

#define GLD16(srcp, ldsp)                                                     \
  __builtin_amdgcn_global_load_lds(                                           \
      (const __attribute__((address_space(1))) unsigned int*)(srcp),          \
      (__attribute__((address_space(3))) unsigned int*)(ldsp), 16, 0, 0)

#define BARRIER()                                                             \
  do {                                                                        \
    __builtin_amdgcn_sched_barrier(0);                                        \
    __builtin_amdgcn_s_barrier();                                             \
    __builtin_amdgcn_sched_barrier(0);                                        \
  } while (0)

#define VMCNT(n) asm volatile("s_waitcnt vmcnt(" #n ")" ::: "memory")

// Byte offset inside a [R rows][32 bf16] tile, row-pair XOR swizzle.
// Storage: row-pair rp (128 B) x 8 slots of 16 B; slot = ((row&1)<<2 | chunk) ^ (rp&7).
// Read pattern (16 lanes, rows R..R+15 (R%16==0), same chunk) -> each slot hit
// exactly twice -> 2-way bank aliasing = free (m136).
__device__ __forceinline__ int swz(int row, int chunk) {
  int slot = (((row & 1) << 2) | chunk) ^ ((row >> 1) & 7);
  return ((row >> 1) << 7) + (slot << 4);
}

// Stage NLOADS*512 16B-chunks (NLOADS*128 rows x 32 bf16) global -> LDS.
// LDS dest is linear (gload_lds HW requirement); the SOURCE address is
// pre-inverse-swizzled so that swz()-reads see a row-major tile (rule #21).
// Local rows > row_max are clamped (duplicate loads into never-read slots).
template <int NLOADS>
__device__ __forceinline__ void stage(const bf16_t* __restrict__ src,
                                      int row_base, int row_max, int k0,
                                      char* ldsb, int tid) {
#pragma unroll
  for (int i = 0; i < NLOADS; ++i) {
    const int c = i * 512 + tid;     // linear 16B-chunk index this thread covers
    const int rp = c >> 3;
    const int slot = c & 7;
    const int v = slot ^ (rp & 7);   // inverse swizzle
    int srow = rp * 2 + (v >> 2);
    if (srow > row_max) srow = row_max;
    const bf16_t* g = src + (size_t)(row_base + srow) * HID + k0 + (v & 3) * 8;
    GLD16(g, ldsb + (size_t)(i * 512 + (tid & ~63)) * 16);  // wave-uniform base
  }
}

// ---------------------------------------------------------------------------
// K1: fp32 -> bf16 conversion of hs, gate_up_w, down_w (contiguous in ws)
// ---------------------------------------------------------------------------
__global__ __launch_bounds__(256) void convert3(const float* __restrict__ a,
                                                const float* __restrict__ b,
                                                const float* __restrict__ c,
                                                bf16_t* __restrict__ o) {
  constexpr size_t na = (size_t)SEQ * HID;
  constexpr size_t nb = (size_t)(2 * INTER) * HID;
  constexpr size_t nc = (size_t)HID * INTER;
  size_t i = ((size_t)blockIdx.x * 256 + threadIdx.x) * 4;
  if (i >= na + nb + nc) return;
  const float* src;
  if (i < na)            src = a + i;
  else if (i < na + nb)  src = b + (i - na);
  else                   src = c + (i - na - nb);
  float4 v = *(const float4*)src;
  bf16x4 r = {(bf16_t)v.x, (bf16_t)v.y, (bf16_t)v.z, (bf16_t)v.w};
  *(bf16x4*)(o + i) = r;
}

// ---------------------------------------------------------------------------
// K2: fused gate/up GEMM + silu.  BM=256, BN=96 (both mats), 8 waves (4M x 2N),
// per-wave 64 x 48 per mat.  LDS slot = A 16K + G 8K + U 8K, ring-4 = 128 KiB.
// Per K-tile: phase0 {read A(4)+G(3); stage (t+3).A; 12 gate MFMA},
//             phase1 {read U(3); stage (t+3).G,(t+3).U; 12 up MFMA; vmcnt(8)}.
// ---------------------------------------------------------------------------
__global__ __launch_bounds__(512, 2) void gemm1(const bf16_t* __restrict__ A,
                                                const bf16_t* __restrict__ GW,
                                                const float* __restrict__ bias,
                                                bf16_t* __restrict__ X) {
  __shared__ char sm[4 * 32768];
  const bf16_t* UW = GW + (size_t)INTER * HID;  // up half of gate_up_w

  const int tid = threadIdx.x;
  const int w = tid >> 6, l = tid & 63;
  const int wm = w >> 1, wn = w & 1;  // 4M x 2N
  const int l15 = l & 15, l4 = l >> 4;
  const int row0 = blockIdx.x * 256;
  const int col0 = blockIdx.y * 96;

  f32x4 accg[4][3], accu[4][3];
#pragma unroll
  for (int m = 0; m < 4; ++m)
#pragma unroll
    for (int n = 0; n < 3; ++n) {
      accg[m][n] = (f32x4){0.f, 0.f, 0.f, 0.f};
      accu[m][n] = (f32x4){0.f, 0.f, 0.f, 0.f};
    }

  // Prologue: stage K-tiles 0,1,2 (4 loads/thread each); retire t0, keep t1,t2.
  for (int t = 0; t < 3; ++t) {
    char* s = sm + t * 32768;
    stage<2>(A, row0, 255, t * BK, s, tid);
    stage<1>(GW, col0, 95, t * BK, s + 16384, tid);
    stage<1>(UW, col0, 95, t * BK, s + 24576, tid);
  }
  VMCNT(8);
  BARRIER();

  for (int t = 0; t < NT; ++t) {
    char* sa = sm + (t & 3) * 32768;
    char* sg = sa + 16384;
    char* su = sa + 24576;
    char* ss = sm + ((t + 3) & 3) * 32768;
    const bool do_stage = (t + 3) < NT;

    // ---- phase 0: gate quadrant ----
    bf16x8 af[4], gf[3];
#pragma unroll
    for (int m = 0; m < 4; ++m)
      af[m] = *(const bf16x8*)(sa + swz(wm * 64 + m * 16 + l15, l4));
#pragma unroll
    for (int n = 0; n < 3; ++n)
      gf[n] = *(const bf16x8*)(sg + swz(wn * 48 + n * 16 + l15, l4));
    if (do_stage) stage<2>(A, row0, 255, (t + 3) * BK, ss, tid);
    BARRIER();
    __builtin_amdgcn_s_setprio(1);
#pragma unroll
    for (int m = 0; m < 4; ++m)
#pragma unroll
      for (int n = 0; n < 3; ++n)
        accg[m][n] = __builtin_amdgcn_mfma_f32_16x16x32_bf16(af[m], gf[n], accg[m][n], 0, 0, 0);
    __builtin_amdgcn_s_setprio(0);
    BARRIER();

    // ---- phase 1: up quadrant ----
    bf16x8 uf[3];
#pragma unroll
    for (int n = 0; n < 3; ++n)
      uf[n] = *(const bf16x8*)(su + swz(wn * 48 + n * 16 + l15, l4));
    if (do_stage) {
      stage<1>(GW, col0, 95, (t + 3) * BK, ss + 16384, tid);
      stage<1>(UW, col0, 95, (t + 3) * BK, ss + 24576, tid);
    }
    BARRIER();
    __builtin_amdgcn_s_setprio(1);
#pragma unroll
    for (int m = 0; m < 4; ++m)
#pragma unroll
      for (int n = 0; n < 3; ++n)
        accu[m][n] = __builtin_amdgcn_mfma_f32_16x16x32_bf16(af[m], uf[n], accu[m][n], 0, 0, 0);
    __builtin_amdgcn_s_setprio(0);
    // Boundary: retire K-tile t+1's 4 loads, keep (t+2),(t+3) = 8 in flight.
    if (t < NT - 3)       { VMCNT(8); }
    else if (t == NT - 3) { VMCNT(4); }
    else if (t == NT - 2) { VMCNT(0); }
    BARRIER();
  }

  // Epilogue: x = (gate+bg) * silu(up+bu); C/D layout col=lane&15,row=(lane>>4)*4+j.
#pragma unroll
  for (int n = 0; n < 3; ++n) {
    const int col = col0 + wn * 48 + n * 16 + l15;
    const float bg = bias[col];
    const float bu = bias[INTER + col];
#pragma unroll
    for (int m = 0; m < 4; ++m) {
      const int r = row0 + wm * 64 + m * 16 + l4 * 4;
#pragma unroll
      for (int j = 0; j < 4; ++j) {
        const float g = accg[m][n][j] + bg;
        const float u = accu[m][n][j] + bu;
        X[(size_t)(r + j) * INTER + col] = (bf16_t)(g * (u / (1.f + __expf(-u))));
      }
    }
  }
}

// ---------------------------------------------------------------------------
// K3: out = x @ down_w^T + down_b.  BM=256, BN=192, 8 waves (4M x 2N),
// per-wave 64 x 96.  LDS slot = A 16K + B 16K (B staged 256 rows, 192 used),
// ring-4 = 128 KiB.  Same counted-vmcnt schedule (4 loads/thread per K-tile).
// ---------------------------------------------------------------------------
__global__ __launch_bounds__(512, 2) void gemm2(const bf16_t* __restrict__ A,
                                                const bf16_t* __restrict__ B,
                                                const float* __restrict__ bias,
                                                float* __restrict__ out) {
  __shared__ char sm[4 * 32768];
  const int tid = threadIdx.x;
  const int w = tid >> 6, l = tid & 63;
  const int wm = w >> 1, wn = w & 1;
  const int l15 = l & 15, l4 = l >> 4;
  const int row0 = blockIdx.x * 256;
  const int col0 = blockIdx.y * 192;

  f32x4 acc[4][6];
#pragma unroll
  for (int m = 0; m < 4; ++m)
#pragma unroll
    for (int n = 0; n < 6; ++n) acc[m][n] = (f32x4){0.f, 0.f, 0.f, 0.f};

  for (int t = 0; t < 3; ++t) {
    char* s = sm + t * 32768;
    stage<2>(A, row0, 255, t * BK, s, tid);
    stage<2>(B, col0, 191, t * BK, s + 16384, tid);
  }
  VMCNT(8);
  BARRIER();

  for (int t = 0; t < NT; ++t) {
    char* sa = sm + (t & 3) * 32768;
    char* sb = sa + 16384;
    char* ss = sm + ((t + 3) & 3) * 32768;
    const bool do_stage = (t + 3) < NT;

    // ---- phase 0: n = 0..2 ----
    bf16x8 af[4], bf0[3];
#pragma unroll
    for (int m = 0; m < 4; ++m)
      af[m] = *(const bf16x8*)(sa + swz(wm * 64 + m * 16 + l15, l4));
#pragma unroll
    for (int n = 0; n < 3; ++n)
      bf0[n] = *(const bf16x8*)(sb + swz(wn * 96 + n * 16 + l15, l4));
    if (do_stage) stage<2>(A, row0, 255, (t + 3) * BK, ss, tid);
    BARRIER();
    __builtin_amdgcn_s_setprio(1);
#pragma unroll
    for (int m = 0; m < 4; ++m)
#pragma unroll
      for (int n = 0; n < 3; ++n)
        acc[m][n] = __builtin_amdgcn_mfma_f32_16x16x32_bf16(af[m], bf0[n], acc[m][n], 0, 0, 0);
    __builtin_amdgcn_s_setprio(0);
    BARRIER();

    // ---- phase 1: n = 3..5 ----
    bf16x8 bf1[3];
#pragma unroll
    for (int n = 0; n < 3; ++n)
      bf1[n] = *(const bf16x8*)(sb + swz(wn * 96 + (n + 3) * 16 + l15, l4));
    if (do_stage) stage<2>(B, col0, 191, (t + 3) * BK, ss + 16384, tid);
    BARRIER();
    __builtin_amdgcn_s_setprio(1);
#pragma unroll
    for (int m = 0; m < 4; ++m)
#pragma unroll
      for (int n = 0; n < 3; ++n)
        acc[m][n + 3] = __builtin_amdgcn_mfma_f32_16x16x32_bf16(af[m], bf1[n], acc[m][n + 3], 0, 0, 0);
    __builtin_amdgcn_s_setprio(0);
    if (t < NT - 3)       { VMCNT(8); }
    else if (t == NT - 3) { VMCNT(4); }
    else if (t == NT - 2) { VMCNT(0); }
    BARRIER();
  }

#pragma unroll
  for (int n = 0; n < 6; ++n) {
    const int col = col0 + wn * 96 + n * 16 + l15;
    const float bb = bias[col];
#pragma unroll
    for (int m = 0; m < 4; ++m) {
      const int r = row0 + wm * 64 + m * 16 + l4 * 4;
#pragma unroll
      for (int j = 0; j < 4; ++j)
        out[(size_t)(r + j) * HID + col] = acc[m][n][j] + bb;
    }
  }
}

// ---------------------------------------------------------------------------
extern "C" void kernel_launch(void* const* d_in, const int* in_sizes, int n_in,
                              void* d_out, int out_size, void* d_ws, size_t ws_size,
                              hipStream_t stream) {
  (void)in_sizes; (void)n_in; (void)out_size; (void)ws_size;

  const float* hs  = (const float*)d_in[0];  // (4096, 2880)
  // d_in[1] router_w, d_in[2] router_b: unused — sum(softmax(topk)) == 1.
  const float* guw = (const float*)d_in[3];  // (5760, 2880)
  const float* gub = (const float*)d_in[4];  // (5760,)
  const float* dww = (const float*)d_in[5];  // (2880, 2880)
  const float* dwb = (const float*)d_in[6];  // (2880,)
  float* out = (float*)d_out;                // (4096, 2880)

  constexpr size_t n_hs  = (size_t)SEQ * HID;
  constexpr size_t n_guw = (size_t)(2 * INTER) * HID;
  constexpr size_t n_dww = (size_t)HID * INTER;

  bf16_t* ws   = (bf16_t*)d_ws;
  bf16_t* hsb  = ws;
  bf16_t* guwb = hsb + n_hs;
  bf16_t* dwwb = guwb + n_guw;
  bf16_t* xb   = dwwb + n_dww;  // (4096, 2880) bf16

  const size_t total4 = (n_hs + n_guw + n_dww) / 4;
  const int cgrid = (int)((total4 + 255) / 256);
  convert3<<<cgrid, 256, 0, stream>>>(hs, guw, dww, ws);

  dim3 g1(SEQ / 256, INTER / 96);   // 16 x 30 = 480 blocks
  gemm1<<<g1, 512, 0, stream>>>(hsb, guwb, gub, xb);

  dim3 g2(SEQ / 256, HID / 192);    // 16 x 15 = 240 blocks
  gemm2<<<g2, 512, 0, stream>>>(xb, dwwb, dwb, out);
}